// Round 6
// baseline (144.765 us; speedup 1.0000x reference)
//
#include <hip/hip_runtime.h>

#define DEVINL __device__ __forceinline__

typedef __attribute__((ext_vector_type(8)))  __bf16         bf16x8;
typedef __attribute__((ext_vector_type(4)))  float          f32x4;
typedef __attribute__((ext_vector_type(16))) float          f32x16;
typedef __attribute__((ext_vector_type(8)))  unsigned short ushort8;
typedef __attribute__((ext_vector_type(4)))  unsigned short ushort4v;
typedef __attribute__((ext_vector_type(4)))  unsigned int   uint4v;
typedef __attribute__((ext_vector_type(4)))  float          float4v;

DEVINL unsigned short f2bf(float f) {
  unsigned int u = __float_as_uint(f);
  u += 0x7fffu + ((u >> 16) & 1u);   // round-to-nearest-even
  return (unsigned short)(u >> 16);
}

DEVINL bf16x8 ldbf8(const unsigned short* p) {
  return __builtin_bit_cast(bf16x8, *(const ushort8*)p);
}

DEVINL unsigned cvtpk_bf16(float lo, float hi) {  // dst.lo16=bf16(lo), dst.hi16=bf16(hi)
  unsigned r;
  asm("v_cvt_pk_bf16_f32 %0, %1, %2" : "=v"(r) : "v"(lo), "v"(hi));
  return r;
}

// async global->LDS, 16B per lane; LDS dest = wave-uniform base + lane*16
DEVINL void gload_lds16(const unsigned short* g, unsigned short* l) {
  __builtin_amdgcn_global_load_lds((const __attribute__((address_space(1))) void*)g,
                                   (__attribute__((address_space(3))) void*)l, 16, 0, 0);
}

// ---------------- fp32 -> bf16 elementwise ----------------
__global__ __launch_bounds__(256) void cvt_f32_bf16_kernel(
    const float* __restrict__ in, unsigned short* __restrict__ out, int n4) {
  int i = blockIdx.x * 256 + threadIdx.x;
  const int stride = gridDim.x * 256;
  for (; i < n4; i += stride) {
    float4v v = *(const float4v*)(in + (size_t)4 * i);
    ushort4v o;
    o[0] = f2bf(v[0]); o[1] = f2bf(v[1]); o[2] = f2bf(v[2]); o[3] = f2bf(v[3]);
    *(ushort4v*)(out + (size_t)4 * i) = o;
  }
}

// ---------------- fp32 (RxC) -> bf16 transposed (CxR) ----------------
__global__ __launch_bounds__(256) void transpose_cvt_kernel(
    const float* __restrict__ in, unsigned short* __restrict__ out, int R, int C) {
  __shared__ float tile[32][33];
  const int tx = threadIdx.x & 31, ty = threadIdx.x >> 5;
  const int r0 = blockIdx.y << 5, c0 = blockIdx.x << 5;
#pragma unroll
  for (int i = 0; i < 32; i += 8)
    tile[ty + i][tx] = in[(size_t)(r0 + ty + i) * C + (c0 + tx)];
  __syncthreads();
#pragma unroll
  for (int i = 0; i < 32; i += 8)
    out[(size_t)(c0 + ty + i) * R + (r0 + tx)] = f2bf(tile[tx][ty + i]);
}

// ---------------- bf16 V transpose: qkv V-third -> Vt[(b,h,d)][s] ----------------
__global__ __launch_bounds__(256) void v_transpose_kernel(
    const unsigned short* __restrict__ qkv, unsigned short* __restrict__ VtG) {
  const int S = 2048, LD = 3072;
  const int s0 = blockIdx.x << 5;
  const int bh = blockIdx.y;           // b*16 + h
  const int b = bh >> 4, h = bh & 15;
  __shared__ __align__(16) unsigned short T[32][72];  // 16B-aligned rows
  const int t = threadIdx.x;
  {
    const int s = t >> 3, d0 = (t & 7) << 3;
    *(ushort8*)&T[s][d0] =
        *(const ushort8*)(qkv + ((size_t)(b * S) + s0 + s) * LD + 2048 + h * 64 + d0);
  }
  __syncthreads();
  {
    const int d = t >> 2, sc = (t & 3) << 3;
    ushort8 o;
#pragma unroll
    for (int e = 0; e < 8; ++e) o[e] = T[sc + e][d];
    *(ushort8*)(VtG + ((size_t)bh * 64 + d) * S + s0 + sc) = o;
  }
}

// ---------------- bf16 GEMM: C = A(MxK) * Bt(NxK)^T ----------------
// 128x128 tile, BK=32, 4 waves (2x2), global_load_lds staging (m97 structure).
template <bool OUT_BF16>
__global__ __launch_bounds__(256) void gemm_bt_kernel(
    const unsigned short* __restrict__ A,   // M x K, lda
    const unsigned short* __restrict__ Bt,  // N x K, ldb
    void* __restrict__ Cout,                // M x N, ldc
    int M, int N, int K, int lda, int ldb, int ldc) {
  __shared__ __align__(16) unsigned short As[128 * 32];
  __shared__ __align__(16) unsigned short Bs[128 * 32];
  const int tid = threadIdx.x;
  const int lane = tid & 63, wave = tid >> 6;
  const int wr = wave >> 1, wc = wave & 1;
  const int g = lane >> 4, q = lane & 15;
  const int row0 = blockIdx.x << 7, col0 = blockIdx.y << 7;

  const int srow = tid >> 2, skcol = (tid & 3) << 3;
  const unsigned short* Ap0 = A + (size_t)(row0 + srow) * lda + skcol;
  const unsigned short* Ap1 = Ap0 + (size_t)64 * lda;
  const unsigned short* Bp0 = Bt + (size_t)(col0 + srow) * ldb + skcol;
  const unsigned short* Bp1 = Bp0 + (size_t)64 * ldb;
  unsigned short* Asw = As + wave * 512;  // wave-uniform LDS base (w*1024 B)
  unsigned short* Bsw = Bs + wave * 512;

  f32x4 acc[4][4] = {};

  for (int k0 = 0; k0 < K; k0 += 32) {
    __syncthreads();               // all waves done reading previous tile
    gload_lds16(Ap0, Asw);
    gload_lds16(Ap1, Asw + 2048);
    gload_lds16(Bp0, Bsw);
    gload_lds16(Bp1, Bsw + 2048);
    Ap0 += 32; Ap1 += 32; Bp0 += 32; Bp1 += 32;
    __syncthreads();               // drains vmcnt -> tile visible

    bf16x8 af[4], bfr[4];
#pragma unroll
    for (int mb = 0; mb < 4; ++mb)
      af[mb] = ldbf8(As + (wr * 64 + mb * 16 + q) * 32 + g * 8);
#pragma unroll
    for (int nb = 0; nb < 4; ++nb)
      bfr[nb] = ldbf8(Bs + (wc * 64 + nb * 16 + q) * 32 + g * 8);
#pragma unroll
    for (int mb = 0; mb < 4; ++mb)
#pragma unroll
      for (int nb = 0; nb < 4; ++nb)
        acc[mb][nb] = __builtin_amdgcn_mfma_f32_16x16x32_bf16(af[mb], bfr[nb], acc[mb][nb], 0, 0, 0);
  }

#pragma unroll
  for (int mb = 0; mb < 4; ++mb)
#pragma unroll
    for (int nb = 0; nb < 4; ++nb)
#pragma unroll
      for (int r = 0; r < 4; ++r) {
        const int row = row0 + wr * 64 + mb * 16 + g * 4 + r;  // C/D: row=(l>>4)*4+reg
        const int col = col0 + wc * 64 + nb * 16 + q;          //       col=l&15
        const float v = acc[mb][nb][r];
        if (OUT_BF16) ((unsigned short*)Cout)[(size_t)row * ldc + col] = f2bf(v);
        else          ((float*)Cout)[(size_t)row * ldc + col] = v;
      }
}

// ---------------- causal flash attention (pipelined, 32x32 MFMA) ----------------
// Block = 4 waves x 32 q-rows. K/V in LDS (dbuf, counted vmcnt, raw barriers, XOR
// swizzle). Swapped QK^T -> S^T in regs. Software pipeline: softmax(t-1)+PV(t-1)
// (register-only) execute while QK(t) MFMAs retire -> MFMA/VALU pipes overlap
// within one wave. In-register P relayout; defer-max softmax; balanced pair grid.
__global__ __launch_bounds__(256, 2) void attn_kernel(
    const unsigned short* __restrict__ qkv,  // (B*S) x 3H row-major
    const unsigned short* __restrict__ VtG,  // (B*16*64) x S : V transposed
    unsigned short* __restrict__ O) {        // (B*S) x H row-major
  const int S = 2048, H = 1024, LD = 3072;
  const int wave = threadIdx.x >> 6, lane = threadIdx.x & 63;
  const int c = lane & 31, hh = lane >> 5;

  // balanced pair decode: CU gets blocks L and L+256 -> qc and 15-qc (34 tiles const)
  const int L = blockIdx.x;
  const int member = L >> 8, r0_ = L & 255;
  const int pairid = r0_ & 7, bh = r0_ >> 3;
  const int qc = member ? (15 - pairid) : pairid;
  const int b = bh >> 4, h = bh & 15;
  const int q0w = qc * 128 + wave * 32;        // this wave's 32 q-rows

  const unsigned short* Qb = qkv + (size_t)b * S * LD + h * 64;
  const unsigned short* Kb = Qb + H;
  const unsigned short* Vt = VtG + (size_t)(b * 16 + h) * 64 * S;

  __shared__ __align__(16) unsigned short Ks[2][64 * 64];   // [kv][d], swizzled
  __shared__ __align__(16) unsigned short Vs[2][64 * 64];   // [d][kv], swizzled

  // staging geometry: 4 x gload_lds16 per wave per tile
  const int srow = lane >> 3;                        // 0..7
  const int srcg = ((lane & 7) ^ srow) << 3;         // pre-swizzled granule (shorts)
  const int wrow = wave * 8 + srow;                  // 0..31

  // prologue: stage tile 0 into buffer 0 (issued before Q loads)
  gload_lds16(Kb + (size_t)wrow * LD + srcg,        Ks[0] + wave * 512);
  gload_lds16(Kb + (size_t)(32 + wrow) * LD + srcg, Ks[0] + 2048 + wave * 512);
  gload_lds16(Vt + (size_t)wrow * S + srcg,         Vs[0] + wave * 512);
  gload_lds16(Vt + (size_t)(32 + wrow) * S + srcg,  Vs[0] + 2048 + wave * 512);

  // Q fragments: lane holds Q[q0w+c][kc*16 + hh*8 + 0..7]
  bf16x8 qf[4];
#pragma unroll
  for (int kc = 0; kc < 4; ++kc)
    qf[kc] = ldbf8(Qb + (size_t)(q0w + c) * LD + kc * 16 + hh * 8);

  f32x16 acc[2] = {};            // O^T: row d = db*32+(r&3)+8(r>>2)+4hh, col = q0w+c
  float m_r = -1e30f, l_r = 0.f; // m uniform across hh pair; l per-lane partial
  const float CE = 0.125f * 1.44269504f;  // 1/sqrt(dh) * log2(e)

  // deferred (previous tile) state — register only
  f32x16 stp[2];
  bf16x8 vfp[2][4];
  int nvp = 0;
  bool havePrev = false;

  // deferred softmax + PV on (stp, vfp, nvp)
  auto do_prev = [&]() {
    f32x4 pm = {-1e30f, -1e30f, -1e30f, -1e30f};
#pragma unroll
    for (int n = 0; n < 2; ++n) if (n < nvp)
#pragma unroll
      for (int r = 0; r < 16; ++r) pm[r & 3] = fmaxf(pm[r & 3], stp[n][r]);
    const float pmax = fmaxf(fmaxf(pm[0], pm[1]), fmaxf(pm[2], pm[3]));
    if (!__all(pmax <= m_r + 64.f)) {   // rare: update running max, rescale
      float px = fmaxf(pmax, __shfl_xor(pmax, 32));
      const float mn = fmaxf(m_r, px);
      const float sf = __builtin_amdgcn_exp2f((m_r - mn) * CE);
      m_r = mn; l_r *= sf;
#pragma unroll
      for (int db = 0; db < 2; ++db) acc[db] *= sf;
    }
    const float mC = m_r * CE;
    f32x4 la = {0.f, 0.f, 0.f, 0.f};
#pragma unroll
    for (int n = 0; n < 2; ++n) if (n < nvp)
#pragma unroll
      for (int r = 0; r < 16; ++r) {
        const float p = __builtin_amdgcn_exp2f(fmaf(stp[n][r], CE, -mC));
        stp[n][r] = p;
        la[r & 3] += p;
      }
    l_r += (la[0] + la[1]) + (la[2] + la[3]);

    // P relayout in-register: cvt_pk pairs then permlane32_swap
    bf16x8 pa[4];
#pragma unroll
    for (int n = 0; n < 2; ++n) if (n < nvp) {
      unsigned T0 = cvtpk_bf16(stp[n][0],  stp[n][1]);
      unsigned T1 = cvtpk_bf16(stp[n][2],  stp[n][3]);
      unsigned T2 = cvtpk_bf16(stp[n][4],  stp[n][5]);
      unsigned T3 = cvtpk_bf16(stp[n][6],  stp[n][7]);
      unsigned T4 = cvtpk_bf16(stp[n][8],  stp[n][9]);
      unsigned T5 = cvtpk_bf16(stp[n][10], stp[n][11]);
      unsigned T6 = cvtpk_bf16(stp[n][12], stp[n][13]);
      unsigned T7 = cvtpk_bf16(stp[n][14], stp[n][15]);
      asm("v_permlane32_swap_b32 %0, %1" : "+v"(T0), "+v"(T2));
      asm("v_permlane32_swap_b32 %0, %1" : "+v"(T1), "+v"(T3));
      asm("v_permlane32_swap_b32 %0, %1" : "+v"(T4), "+v"(T6));
      asm("v_permlane32_swap_b32 %0, %1" : "+v"(T5), "+v"(T7));
      uint4v w0; w0[0] = T0; w0[1] = T1; w0[2] = T2; w0[3] = T3;
      uint4v w1; w1[0] = T4; w1[1] = T5; w1[2] = T6; w1[3] = T7;
      pa[2 * n]     = __builtin_bit_cast(bf16x8, w0);
      pa[2 * n + 1] = __builtin_bit_cast(bf16x8, w1);
    }

    // O^T += V^T P
#pragma unroll
    for (int kk = 0; kk < 4; ++kk) if (kk < 2 * nvp)
#pragma unroll
      for (int db = 0; db < 2; ++db)
        acc[db] = __builtin_amdgcn_mfma_f32_32x32x16_bf16(vfp[db][kk], pa[kk], acc[db], 0, 0, 0);
  };

  const int ntb = qc * 2 + 2;    // KV tiles this block processes
  int cur = 0;
  const int swz = (c & 7) << 3;  // read-side XOR (shorts)

  for (int t = 0; t < ntb; ++t) {
    if (t + 1 < ntb) {           // issue next tile's loads; stay in flight
      const int c1 = (t + 1) << 6;
      unsigned short* KsN = Ks[cur ^ 1];
      unsigned short* VsN = Vs[cur ^ 1];
      gload_lds16(Kb + (size_t)(c1 + wrow) * LD + srcg,      KsN + wave * 512);
      gload_lds16(Kb + (size_t)(c1 + 32 + wrow) * LD + srcg, KsN + 2048 + wave * 512);
      gload_lds16(Vt + (size_t)wrow * S + c1 + srcg,         VsN + wave * 512);
      gload_lds16(Vt + (size_t)(32 + wrow) * S + c1 + srcg,  VsN + 2048 + wave * 512);
      asm volatile("s_waitcnt vmcnt(4)" ::: "memory");   // tile t resident
    } else {
      asm volatile("s_waitcnt vmcnt(0)" ::: "memory");
    }
    __builtin_amdgcn_s_barrier();  // all waves' stage(t) visible

    const int c0 = t << 6;
    const unsigned short* KsC = Ks[cur];
    const unsigned short* VsC = Vs[cur];
    const bool act = (c0 <= q0w + 31);  // wave-uniform

    f32x16 stc[2] = {};
    bf16x8 vfc[2][4];
    int nv = 0;

    if (act) {
      nv = ((q0w + 31 - c0) >> 5) + 1; if (nv > 2) nv = 2;  // valid 32-kv chunks

      // K fragments: A-operand rows kv = n*32+c, k = kc*16+hh*8
      bf16x8 kf[2][4];
#pragma unroll
      for (int n = 0; n < 2; ++n) if (n < nv)
#pragma unroll
        for (int kc = 0; kc < 4; ++kc)
          kf[n][kc] = ldbf8(KsC + (n * 32 + c) * 64 + ((kc * 16 + hh * 8) ^ swz));

      // S^T = K Q^T (MFMA pipe busy while deferred softmax runs below)
#pragma unroll
      for (int n = 0; n < 2; ++n) if (n < nv)
#pragma unroll
        for (int kc = 0; kc < 4; ++kc)
          stc[n] = __builtin_amdgcn_mfma_f32_32x32x16_bf16(kf[n][kc], qf[kc], stc[n], 0, 0, 0);

      // V fragments for THIS tile (consumed next iteration, register-carried)
#pragma unroll
      for (int db = 0; db < 2; ++db)
#pragma unroll
        for (int kk = 0; kk < 4; ++kk) if (kk < 2 * nv)
          vfc[db][kk] = ldbf8(VsC + (db * 32 + c) * 64 + ((kk * 16 + hh * 8) ^ swz));
    }

    if (havePrev) { do_prev(); havePrev = false; }  // softmax(t-1)+PV(t-1), reg-only

    if (act) {
      if (c0 + 63 > q0w) {  // causal mask (diag region only)
#pragma unroll
        for (int n = 0; n < 2; ++n) if (n < nv)
#pragma unroll
          for (int r = 0; r < 16; ++r) {
            const int kv = c0 + n * 32 + (r & 3) + 8 * (r >> 2) + 4 * hh;
            if (kv > q0w + c) stc[n][r] = -1e30f;
          }
      }
      stp[0] = stc[0]; stp[1] = stc[1];
#pragma unroll
      for (int db = 0; db < 2; ++db)
#pragma unroll
        for (int kk = 0; kk < 4; ++kk) vfp[db][kk] = vfc[db][kk];
      nvp = nv;
      havePrev = true;
    }

    __builtin_amdgcn_s_barrier();  // all waves done reading buf[cur]
    cur ^= 1;
  }

  if (havePrev) do_prev();  // drain the pipeline

  // epilogue: O[qrow][d] = O^T[d][qrow]/l ; 8B packed stores
  const float lt = l_r + __shfl_xor(l_r, 32);
  const float inv = 1.f / lt;
  const size_t rowbase = (size_t)(b * S + q0w + c) * H + h * 64;
#pragma unroll
  for (int db = 0; db < 2; ++db)
#pragma unroll
    for (int blk = 0; blk < 4; ++blk) {
      ushort4v o;
#pragma unroll
      for (int j = 0; j < 4; ++j) o[j] = f2bf(acc[db][blk * 4 + j] * inv);
      *(ushort4v*)(O + rowbase + db * 32 + blk * 8 + hh * 4) = o;
    }
}

extern "C" void kernel_launch(void* const* d_in, const int* in_sizes, int n_in,
                              void* d_out, int out_size, void* d_ws, size_t ws_size,
                              hipStream_t stream) {
  const float* x     = (const float*)d_in[0];
  const float* w_qkv = (const float*)d_in[1];
  const float* w_out = (const float*)d_in[2];
  const int B = 2, S = 2048, H = 1024;
  const int M = B * S;  // 4096

  // workspace layout (ushort elements), total 48 MB:
  unsigned short* xb    = (unsigned short*)d_ws;        // M*H   (8 MB)  -> reused as VtG
  unsigned short* wqkvT = xb + (size_t)M * H;           // 3H*H  (6 MB)
  unsigned short* woutT = wqkvT + (size_t)3 * H * H;    // H*H   (2 MB)
  unsigned short* qkvb  = woutT + (size_t)H * H;        // M*3H (24 MB)
  unsigned short* Ob    = qkvb + (size_t)M * 3 * H;     // M*H   (8 MB)
  unsigned short* VtG   = xb;  // x-bf16 dead after QKV GEMM; reuse for V^T

  cvt_f32_bf16_kernel<<<1024, 256, 0, stream>>>(x, xb, (M * H) / 4);
  transpose_cvt_kernel<<<dim3((3 * H) / 32, H / 32), 256, 0, stream>>>(w_qkv, wqkvT, H, 3 * H);
  transpose_cvt_kernel<<<dim3(H / 32, H / 32), 256, 0, stream>>>(w_out, woutT, H, H);

  // qkv = x @ w_qkv  (bf16 out, feeds attention)
  gemm_bt_kernel<true><<<dim3(M / 128, (3 * H) / 128), 256, 0, stream>>>(
      xb, wqkvT, qkvb, M, 3 * H, H, H, H, 3 * H);

  // V -> (b,h,d,s) transposed layout (PV A-operand becomes direct LDS-staged loads)
  v_transpose_kernel<<<dim3(S / 32, 32), 256, 0, stream>>>(qkvb, VtG);

  // causal multi-head attention (512 balanced blocks)
  attn_kernel<<<512, 256, 0, stream>>>(qkvb, VtG, Ob);

  // out = attn @ w_out (fp32 out)
  gemm_bt_kernel<false><<<dim3(M / 128, H / 128), 256, 0, stream>>>(
      Ob, woutT, d_out, M, H, H, H, H, H);
}

// Round 7
// 131.216 us; speedup vs baseline: 1.1033x; 1.1033x over previous
//
#include <hip/hip_runtime.h>

#define DEVINL __device__ __forceinline__

typedef __attribute__((ext_vector_type(8)))  __bf16         bf16x8;
typedef __attribute__((ext_vector_type(4)))  float          f32x4;
typedef __attribute__((ext_vector_type(16))) float          f32x16;
typedef __attribute__((ext_vector_type(8)))  unsigned short ushort8;
typedef __attribute__((ext_vector_type(4)))  unsigned short ushort4v;
typedef __attribute__((ext_vector_type(4)))  unsigned int   uint4v;
typedef __attribute__((ext_vector_type(4)))  float          float4v;

DEVINL unsigned short f2bf(float f) {
  unsigned int u = __float_as_uint(f);
  u += 0x7fffu + ((u >> 16) & 1u);   // round-to-nearest-even
  return (unsigned short)(u >> 16);
}

DEVINL bf16x8 ldbf8(const unsigned short* p) {
  return __builtin_bit_cast(bf16x8, *(const ushort8*)p);
}

DEVINL unsigned cvtpk_bf16(float lo, float hi) {  // dst.lo16=bf16(lo), dst.hi16=bf16(hi)
  unsigned r;
  asm("v_cvt_pk_bf16_f32 %0, %1, %2" : "=v"(r) : "v"(lo), "v"(hi));
  return r;
}

// async global->LDS, 16B per lane; LDS dest = wave-uniform base + lane*16
DEVINL void gload_lds16(const unsigned short* g, unsigned short* l) {
  __builtin_amdgcn_global_load_lds((const __attribute__((address_space(1))) void*)g,
                                   (__attribute__((address_space(3))) void*)l, 16, 0, 0);
}

// ---------------- fp32 -> bf16 elementwise ----------------
__global__ __launch_bounds__(256) void cvt_f32_bf16_kernel(
    const float* __restrict__ in, unsigned short* __restrict__ out, int n4) {
  int i = blockIdx.x * 256 + threadIdx.x;
  const int stride = gridDim.x * 256;
  for (; i < n4; i += stride) {
    float4v v = *(const float4v*)(in + (size_t)4 * i);
    ushort4v o;
    o[0] = f2bf(v[0]); o[1] = f2bf(v[1]); o[2] = f2bf(v[2]); o[3] = f2bf(v[3]);
    *(ushort4v*)(out + (size_t)4 * i) = o;
  }
}

// ---------------- fp32 (RxC) -> bf16 transposed (CxR) ----------------
__global__ __launch_bounds__(256) void transpose_cvt_kernel(
    const float* __restrict__ in, unsigned short* __restrict__ out, int R, int C) {
  __shared__ float tile[32][33];
  const int tx = threadIdx.x & 31, ty = threadIdx.x >> 5;
  const int r0 = blockIdx.y << 5, c0 = blockIdx.x << 5;
#pragma unroll
  for (int i = 0; i < 32; i += 8)
    tile[ty + i][tx] = in[(size_t)(r0 + ty + i) * C + (c0 + tx)];
  __syncthreads();
#pragma unroll
  for (int i = 0; i < 32; i += 8)
    out[(size_t)(c0 + ty + i) * R + (r0 + tx)] = f2bf(tile[tx][ty + i]);
}

// ---------------- bf16 V transpose: qkv V-third -> Vt[(b,h,d)][s] ----------------
__global__ __launch_bounds__(256) void v_transpose_kernel(
    const unsigned short* __restrict__ qkv, unsigned short* __restrict__ VtG) {
  const int S = 2048, LD = 3072;
  const int s0 = blockIdx.x << 5;
  const int bh = blockIdx.y;           // b*16 + h
  const int b = bh >> 4, h = bh & 15;
  __shared__ __align__(16) unsigned short T[32][72];  // 16B-aligned rows
  const int t = threadIdx.x;
  {
    const int s = t >> 3, d0 = (t & 7) << 3;
    *(ushort8*)&T[s][d0] =
        *(const ushort8*)(qkv + ((size_t)(b * S) + s0 + s) * LD + 2048 + h * 64 + d0);
  }
  __syncthreads();
  {
    const int d = t >> 2, sc = (t & 3) << 3;
    ushort8 o;
#pragma unroll
    for (int e = 0; e < 8; ++e) o[e] = T[sc + e][d];
    *(ushort8*)(VtG + ((size_t)bh * 64 + d) * S + s0 + sc) = o;
  }
}

// ---------------- bf16 GEMM: C = A(MxK) * Bt(NxK)^T ----------------
// 128x128 tile, BK=32, 4 waves (2x2). Double-buffered LDS via global_load_lds +
// counted vmcnt(4) + raw barriers (prefetch never drained). Granule XOR swizzle
// (src pre-swizzled, read-side XOR is per-lane constant) cuts 8-way conflicts to 4.
template <bool OUT_BF16>
__global__ __launch_bounds__(256, 3) void gemm_bt_kernel(
    const unsigned short* __restrict__ A,   // M x K, lda
    const unsigned short* __restrict__ Bt,  // N x K, ldb
    void* __restrict__ Cout,                // M x N, ldc
    int M, int N, int K, int lda, int ldb, int ldc) {
  __shared__ __align__(16) unsigned short As[2][128 * 32];
  __shared__ __align__(16) unsigned short Bs[2][128 * 32];
  const int tid = threadIdx.x;
  const int lane = tid & 63, wave = tid >> 6;
  const int wr = wave >> 1, wc = wave & 1;
  const int g = lane >> 4, q = lane & 15;
  const int row0 = blockIdx.x << 7, col0 = blockIdx.y << 7;

  // staging: thread t covers row srow, pre-swizzled granule (tid&3)^(srow&3)
  const int srow = tid >> 2;
  const int sg = ((tid & 3) ^ (srow & 3)) << 3;   // shorts
  const unsigned short* Ap0 = A + (size_t)(row0 + srow) * lda + sg;
  const unsigned short* Ap1 = Ap0 + (size_t)64 * lda;
  const unsigned short* Bp0 = Bt + (size_t)(col0 + srow) * ldb + sg;
  const unsigned short* Bp1 = Bp0 + (size_t)64 * ldb;

  f32x4 acc[4][4] = {};

  // prologue: stage K-tile 0 into buffer 0
  gload_lds16(Ap0, &As[0][wave * 512]);
  gload_lds16(Ap1, &As[0][2048 + wave * 512]);
  gload_lds16(Bp0, &Bs[0][wave * 512]);
  gload_lds16(Bp1, &Bs[0][2048 + wave * 512]);

  const int gx = (g ^ (q & 3)) << 3;  // read-side swizzled granule offset (shorts)
  const int nk = K >> 5;
  int cur = 0;

  for (int t = 0; t < nk; ++t) {
    if (t + 1 < nk) {                 // issue next K-tile; stays in flight
      Ap0 += 32; Ap1 += 32; Bp0 += 32; Bp1 += 32;
      gload_lds16(Ap0, &As[cur ^ 1][wave * 512]);
      gload_lds16(Ap1, &As[cur ^ 1][2048 + wave * 512]);
      gload_lds16(Bp0, &Bs[cur ^ 1][wave * 512]);
      gload_lds16(Bp1, &Bs[cur ^ 1][2048 + wave * 512]);
      asm volatile("s_waitcnt vmcnt(4)" ::: "memory");   // tile t resident
    } else {
      asm volatile("s_waitcnt vmcnt(0)" ::: "memory");
    }
    __builtin_amdgcn_s_barrier();     // all waves' stage(t) visible

    bf16x8 af[4], bfr[4];
#pragma unroll
    for (int mb = 0; mb < 4; ++mb)
      af[mb] = ldbf8(&As[cur][(wr * 64 + mb * 16 + q) * 32] + gx);
#pragma unroll
    for (int nb = 0; nb < 4; ++nb)
      bfr[nb] = ldbf8(&Bs[cur][(wc * 64 + nb * 16 + q) * 32] + gx);
#pragma unroll
    for (int mb = 0; mb < 4; ++mb)
#pragma unroll
      for (int nb = 0; nb < 4; ++nb)
        acc[mb][nb] = __builtin_amdgcn_mfma_f32_16x16x32_bf16(af[mb], bfr[nb], acc[mb][nb], 0, 0, 0);

    __builtin_amdgcn_s_barrier();     // all waves done reading buf[cur]
    cur ^= 1;
  }

#pragma unroll
  for (int mb = 0; mb < 4; ++mb)
#pragma unroll
    for (int nb = 0; nb < 4; ++nb)
#pragma unroll
      for (int r = 0; r < 4; ++r) {
        const int row = row0 + wr * 64 + mb * 16 + g * 4 + r;  // C/D: row=(l>>4)*4+reg
        const int col = col0 + wc * 64 + nb * 16 + q;          //       col=l&15
        const float v = acc[mb][nb][r];
        if (OUT_BF16) ((unsigned short*)Cout)[(size_t)row * ldc + col] = f2bf(v);
        else          ((float*)Cout)[(size_t)row * ldc + col] = v;
      }
}

// ---------------- causal flash attention (32x32 MFMA, in-register P) ----------------
// Block = 4 waves x 32 q-rows. K/V staged in LDS (dbuf, counted vmcnt, raw barrier,
// XOR swizzle). Swapped QK^T -> S^T; in-register P via cvt_pk + permlane32_swap.
// Defer-max online softmax (zero cross-lane in common path). Linear grid with
// pair-decode so each CU's 2 resident blocks sum to constant work (qc + 15-qc).
__global__ __launch_bounds__(256, 2) void attn_kernel(
    const unsigned short* __restrict__ qkv,  // (B*S) x 3H row-major
    const unsigned short* __restrict__ VtG,  // (B*16*64) x S : V transposed
    unsigned short* __restrict__ O) {        // (B*S) x H row-major
  const int S = 2048, H = 1024, LD = 3072;
  const int wave = threadIdx.x >> 6, lane = threadIdx.x & 63;
  const int c = lane & 31, hh = lane >> 5;

  // balanced pair decode: CU gets blocks L and L+256 -> qc and 15-qc (34 tiles const)
  const int L = blockIdx.x;
  const int member = L >> 8, r0_ = L & 255;
  const int pairid = r0_ & 7, bh = r0_ >> 3;
  const int qc = member ? (15 - pairid) : pairid;
  const int b = bh >> 4, h = bh & 15;
  const int q0w = qc * 128 + wave * 32;        // this wave's 32 q-rows

  const unsigned short* Qb = qkv + (size_t)b * S * LD + h * 64;
  const unsigned short* Kb = Qb + H;
  const unsigned short* Vt = VtG + (size_t)(b * 16 + h) * 64 * S;

  __shared__ __align__(16) unsigned short Ks[2][64 * 64];   // [kv][d], swizzled
  __shared__ __align__(16) unsigned short Vs[2][64 * 64];   // [d][kv], swizzled

  // staging geometry: 4 x gload_lds16 per wave per tile
  const int srow = lane >> 3;                        // 0..7
  const int srcg = ((lane & 7) ^ srow) << 3;         // pre-swizzled granule (shorts)
  const int wrow = wave * 8 + srow;                  // 0..31

  // prologue: stage tile 0 into buffer 0 (issued before Q loads)
  gload_lds16(Kb + (size_t)wrow * LD + srcg,        Ks[0] + wave * 512);
  gload_lds16(Kb + (size_t)(32 + wrow) * LD + srcg, Ks[0] + 2048 + wave * 512);
  gload_lds16(Vt + (size_t)wrow * S + srcg,         Vs[0] + wave * 512);
  gload_lds16(Vt + (size_t)(32 + wrow) * S + srcg,  Vs[0] + 2048 + wave * 512);

  // Q fragments: lane holds Q[q0w+c][kc*16 + hh*8 + 0..7]
  bf16x8 qf[4];
#pragma unroll
  for (int kc = 0; kc < 4; ++kc)
    qf[kc] = ldbf8(Qb + (size_t)(q0w + c) * LD + kc * 16 + hh * 8);

  f32x16 acc[2] = {};            // O^T: row d = db*32+(r&3)+8(r>>2)+4hh, col = q0w+c
  float m_r = -1e30f, l_r = 0.f; // m uniform across hh pair; l per-lane partial
  const float CE = 0.125f * 1.44269504f;  // 1/sqrt(dh) * log2(e)

  const int ntb = qc * 2 + 2;    // KV tiles this block processes
  int cur = 0;
  const int swz = (c & 7) << 3;  // read-side XOR (shorts)

  for (int t = 0; t < ntb; ++t) {
    if (t + 1 < ntb) {           // issue next tile's loads; stay in flight
      const int c1 = (t + 1) << 6;
      unsigned short* KsN = Ks[cur ^ 1];
      unsigned short* VsN = Vs[cur ^ 1];
      gload_lds16(Kb + (size_t)(c1 + wrow) * LD + srcg,      KsN + wave * 512);
      gload_lds16(Kb + (size_t)(c1 + 32 + wrow) * LD + srcg, KsN + 2048 + wave * 512);
      gload_lds16(Vt + (size_t)wrow * S + c1 + srcg,         VsN + wave * 512);
      gload_lds16(Vt + (size_t)(32 + wrow) * S + c1 + srcg,  VsN + 2048 + wave * 512);
      asm volatile("s_waitcnt vmcnt(4)" ::: "memory");   // tile t resident
    } else {
      asm volatile("s_waitcnt vmcnt(0)" ::: "memory");
    }
    __builtin_amdgcn_s_barrier();  // all waves' stage(t) visible

    const int c0 = t << 6;
    const unsigned short* KsC = Ks[cur];
    const unsigned short* VsC = Vs[cur];

    if (c0 <= q0w + 31) {  // wave has unmasked rows in this tile
      int nv = ((q0w + 31 - c0) >> 5) + 1; if (nv > 2) nv = 2;  // valid 32-kv chunks

      // K fragments: A-operand rows kv = n*32+c, k = kc*16+hh*8
      bf16x8 kf[2][4];
#pragma unroll
      for (int n = 0; n < 2; ++n) if (n < nv)
#pragma unroll
        for (int kc = 0; kc < 4; ++kc)
          kf[n][kc] = ldbf8(KsC + (n * 32 + c) * 64 + ((kc * 16 + hh * 8) ^ swz));

      // S^T = K Q^T : st[n] rows kv, cols qrow
      f32x16 st[2] = {};
#pragma unroll
      for (int n = 0; n < 2; ++n) if (n < nv)
#pragma unroll
        for (int kc = 0; kc < 4; ++kc)
          st[n] = __builtin_amdgcn_mfma_f32_32x32x16_bf16(kf[n][kc], qf[kc], st[n], 0, 0, 0);

      // V fragments early (latency hides under softmax): rows d = db*32+c
      bf16x8 vf[2][4];
#pragma unroll
      for (int db = 0; db < 2; ++db)
#pragma unroll
        for (int kk = 0; kk < 4; ++kk) if (kk < 2 * nv)
          vf[db][kk] = ldbf8(VsC + (db * 32 + c) * 64 + ((kk * 16 + hh * 8) ^ swz));

      if (c0 + 63 > q0w) {  // causal mask (diag region only)
#pragma unroll
        for (int n = 0; n < 2; ++n) if (n < nv)
#pragma unroll
          for (int r = 0; r < 16; ++r) {
            const int kv = c0 + n * 32 + (r & 3) + 8 * (r >> 2) + 4 * hh;
            if (kv > q0w + c) st[n][r] = -1e30f;
          }
      }

      // defer-max online softmax (raw-score domain; 64 raw = 11.5 bits of exp2)
      float pmax = -1e30f;
#pragma unroll
      for (int n = 0; n < 2; ++n) if (n < nv)
#pragma unroll
        for (int r = 0; r < 16; ++r) pmax = fmaxf(pmax, st[n][r]);
      if (!__all(pmax <= m_r + 64.f)) {   // rare: update running max, rescale
        pmax = fmaxf(pmax, __shfl_xor(pmax, 32));
        const float mn = fmaxf(m_r, pmax);
        const float sf = __builtin_amdgcn_exp2f((m_r - mn) * CE);
        m_r = mn; l_r *= sf;
#pragma unroll
        for (int db = 0; db < 2; ++db) acc[db] *= sf;
      }
      const float mC = m_r * CE;
#pragma unroll
      for (int n = 0; n < 2; ++n) if (n < nv)
#pragma unroll
        for (int r = 0; r < 16; ++r) {
          const float p = __builtin_amdgcn_exp2f(fmaf(st[n][r], CE, -mC));
          st[n][r] = p;
          l_r += p;
        }

      // P relayout in-register: cvt_pk pairs then permlane32_swap
      bf16x8 pa[4];
#pragma unroll
      for (int n = 0; n < 2; ++n) if (n < nv) {
        unsigned T0 = cvtpk_bf16(st[n][0],  st[n][1]);
        unsigned T1 = cvtpk_bf16(st[n][2],  st[n][3]);
        unsigned T2 = cvtpk_bf16(st[n][4],  st[n][5]);
        unsigned T3 = cvtpk_bf16(st[n][6],  st[n][7]);
        unsigned T4 = cvtpk_bf16(st[n][8],  st[n][9]);
        unsigned T5 = cvtpk_bf16(st[n][10], st[n][11]);
        unsigned T6 = cvtpk_bf16(st[n][12], st[n][13]);
        unsigned T7 = cvtpk_bf16(st[n][14], st[n][15]);
        asm("v_permlane32_swap_b32 %0, %1" : "+v"(T0), "+v"(T2));
        asm("v_permlane32_swap_b32 %0, %1" : "+v"(T1), "+v"(T3));
        asm("v_permlane32_swap_b32 %0, %1" : "+v"(T4), "+v"(T6));
        asm("v_permlane32_swap_b32 %0, %1" : "+v"(T5), "+v"(T7));
        uint4v w0; w0[0] = T0; w0[1] = T1; w0[2] = T2; w0[3] = T3;
        uint4v w1; w1[0] = T4; w1[1] = T5; w1[2] = T6; w1[3] = T7;
        pa[2 * n]     = __builtin_bit_cast(bf16x8, w0);
        pa[2 * n + 1] = __builtin_bit_cast(bf16x8, w1);
      }

      // O^T += V^T P
#pragma unroll
      for (int kk = 0; kk < 4; ++kk) if (kk < 2 * nv)
#pragma unroll
        for (int db = 0; db < 2; ++db)
          acc[db] = __builtin_amdgcn_mfma_f32_32x32x16_bf16(vf[db][kk], pa[kk], acc[db], 0, 0, 0);
    }

    __builtin_amdgcn_s_barrier();  // all waves done reading buf[cur]
    cur ^= 1;
  }

  // epilogue: O[qrow][d] = O^T[d][qrow]/l ; 8B packed stores
  const float lt = l_r + __shfl_xor(l_r, 32);
  const float inv = 1.f / lt;
  const size_t rowbase = (size_t)(b * S + q0w + c) * H + h * 64;
#pragma unroll
  for (int db = 0; db < 2; ++db)
#pragma unroll
    for (int blk = 0; blk < 4; ++blk) {
      ushort4v o;
#pragma unroll
      for (int j = 0; j < 4; ++j) o[j] = f2bf(acc[db][blk * 4 + j] * inv);
      *(ushort4v*)(O + rowbase + db * 32 + blk * 8 + hh * 4) = o;
    }
}

extern "C" void kernel_launch(void* const* d_in, const int* in_sizes, int n_in,
                              void* d_out, int out_size, void* d_ws, size_t ws_size,
                              hipStream_t stream) {
  const float* x     = (const float*)d_in[0];
  const float* w_qkv = (const float*)d_in[1];
  const float* w_out = (const float*)d_in[2];
  const int B = 2, S = 2048, H = 1024;
  const int M = B * S;  // 4096

  // workspace layout (ushort elements), total 48 MB:
  unsigned short* xb    = (unsigned short*)d_ws;        // M*H   (8 MB)  -> reused as VtG
  unsigned short* wqkvT = xb + (size_t)M * H;           // 3H*H  (6 MB)
  unsigned short* woutT = wqkvT + (size_t)3 * H * H;    // H*H   (2 MB)
  unsigned short* qkvb  = woutT + (size_t)H * H;        // M*3H (24 MB)
  unsigned short* Ob    = qkvb + (size_t)M * 3 * H;     // M*H   (8 MB)
  unsigned short* VtG   = xb;  // x-bf16 dead after QKV GEMM; reuse for V^T

  cvt_f32_bf16_kernel<<<1024, 256, 0, stream>>>(x, xb, (M * H) / 4);
  transpose_cvt_kernel<<<dim3((3 * H) / 32, H / 32), 256, 0, stream>>>(w_qkv, wqkvT, H, 3 * H);
  transpose_cvt_kernel<<<dim3(H / 32, H / 32), 256, 0, stream>>>(w_out, woutT, H, H);

  // qkv = x @ w_qkv  (bf16 out, feeds attention)
  gemm_bt_kernel<true><<<dim3(M / 128, (3 * H) / 128), 256, 0, stream>>>(
      xb, wqkvT, qkvb, M, 3 * H, H, H, H, 3 * H);

  // V -> (b,h,d,s) transposed layout (PV A-operand becomes direct LDS-staged loads)
  v_transpose_kernel<<<dim3(S / 32, 32), 256, 0, stream>>>(qkvb, VtG);

  // causal multi-head attention (512 balanced blocks)
  attn_kernel<<<512, 256, 0, stream>>>(qkvb, VtG, Ob);

  // out = attn @ w_out (fp32 out)
  gemm_bt_kernel<false><<<dim3(M / 128, H / 128), 256, 0, stream>>>(
      Ob, woutT, d_out, M, H, H, H, H, H);
}